// Round 5
// baseline (196.594 us; speedup 1.0000x reference)
//
#include <hip/hip_runtime.h>
#include <hip/hip_bf16.h>
#include <cstdint>

// ---------------------------------------------------------------------------
// SAGE GNN, 2 layers, N=50000, E=800000, D: 128 -> 256 -> 128.
// CSR build, fully atomic-free at global scope (deterministic 2-level sort):
//   bhist:   per-block LDS hist over dst-buckets -> blockhist[pb][1024] stores
//   colscan: per-bucket serial scan over blocks -> per-(block,bucket) prefix
//            (in place) + column totals bhist[1024]
//   bscan:   exclusive scan of bucket totals -> brow[0..NB]
//   bin2:    cursors = brow + own prefix row (LDS), place packed 4B entries
//            (src:16 | dst&63:16) -> bucket-sorted stage
//   scatter2b: block per bucket; per-node deg+scan in LDS -> rowptr, col(u16)
// Dense path:
//   A1[:,128:256] = bf16(x); A1[:,0:128] = mean_in(bf16 x)
//   h   = relu(A1 @ [[W1_l],[W1_r]] + b1)   bf16 MFMA GEMM, K=256,N=256
//   hw2 = h @ [W2_l | W2_r]                 bf16 MFMA GEMM
//   out = mean_in(hw2[:,:128]) + hw2[:,128:] + b2
// Packing requires N <= 65536 (problem fixes N=50000).
// ---------------------------------------------------------------------------

static inline size_t align_up(size_t x, size_t a) { return (x + a - 1) & ~(a - 1); }

using short8 = __attribute__((ext_vector_type(8))) short;
using f32x4  = __attribute__((ext_vector_type(4))) float;

#define BSHIFT 6   // 64 nodes per bucket; NB = ceil(N/64) = 782 (<= 1024)
#define PB 98      // partition blocks for hist/bin

__device__ __forceinline__ float bfpair_lo(unsigned int v) {
  union { unsigned int i; float f; } u; u.i = v << 16; return u.f;
}
__device__ __forceinline__ float bfpair_hi(unsigned int v) {
  union { unsigned int i; float f; } u; u.i = v & 0xffff0000u; return u.f;
}
__device__ __forceinline__ unsigned short f2bf(float f) {
  union { float f; unsigned int i; } u; u.f = f;
  unsigned int r = u.i + 0x7fffu + ((u.i >> 16) & 1u);
  return (unsigned short)(r >> 16);
}

__device__ __forceinline__ void gload_lds16(const void* g, void* l) {
  __builtin_amdgcn_global_load_lds(
      (const __attribute__((address_space(1))) void*)g,
      (__attribute__((address_space(3))) void*)l, 16, 0, 0);
}

// ------------------------------- CSR build ---------------------------------

// per-block LDS bucket histogram -> PLAIN coalesced stores of the full row
__global__ __launch_bounds__(256) void bhist_kernel(const int* __restrict__ dst,
                                                    int* __restrict__ blockhist,
                                                    int E, int chunk) {
  __shared__ int h[1024];
  const int t = threadIdx.x;
  const int pb = blockIdx.x;
  #pragma unroll
  for (int i = t; i < 1024; i += 256) h[i] = 0;
  __syncthreads();
  const int e0 = pb * chunk;
  int e1 = e0 + chunk; if (e1 > E) e1 = E;
  for (int e = e0 + t; e < e1; e += 256) atomicAdd(&h[dst[e] >> BSHIFT], 1);
  __syncthreads();
  #pragma unroll
  for (int i = t; i < 1024; i += 256) blockhist[pb * 1024 + i] = h[i];
}

// 1024 threads (<<<4,256>>>): for bucket i, serial scan over PB blocks:
// blockhist[pb][i] <- prefix-before-pb ; bhist[i] <- total
__global__ __launch_bounds__(256) void colscan_kernel(int* __restrict__ blockhist,
                                                      int* __restrict__ bhist) {
  const int i = blockIdx.x * 256 + threadIdx.x;  // 0..1023
  int run = 0;
  for (int pb = 0; pb < PB; ++pb) {
    int v = blockhist[pb * 1024 + i];
    blockhist[pb * 1024 + i] = run;
    run += v;
  }
  bhist[i] = run;
}

// one block, 256 threads x int4: exclusive scan of bhist[0..1024) -> brow
__global__ __launch_bounds__(256) void bscan_kernel(const int* __restrict__ bhist,
                                                    int* __restrict__ brow, int NB) {
  const int t = threadIdx.x;
  int4 v = *reinterpret_cast<const int4*>(bhist + t * 4);
  int tsum = v.x + v.y + v.z + v.w;
  const int lane = t & 63, w = t >> 6;
  int inc = tsum;
  #pragma unroll
  for (int off = 1; off < 64; off <<= 1) {
    int u = __shfl_up(inc, off, 64);
    if (lane >= off) inc += u;
  }
  __shared__ int wsum[4];
  if (lane == 63) wsum[w] = inc;
  __syncthreads();
  int woff = 0;
  for (int i = 0; i < w; ++i) woff += wsum[i];
  int e0 = woff + inc - tsum;
  const int base = t * 4;
  int p[4];
  p[0] = e0;
  p[1] = e0 + v.x;
  p[2] = p[1] + v.y;
  p[3] = p[2] + v.z;
  #pragma unroll
  for (int j = 0; j < 4; ++j)
    if (base + j < NB) brow[base + j] = p[j];
  if (t == 0) brow[NB] = wsum[0] + wsum[1] + wsum[2] + wsum[3];
}

// cursors = brow + own prefix (no global atomics); place packed 4B entries
__global__ __launch_bounds__(256) void bin2_kernel(const int* __restrict__ src,
                                                   const int* __restrict__ dst,
                                                   const int* __restrict__ brow,
                                                   const int* __restrict__ blockhist,
                                                   unsigned* __restrict__ stage,
                                                   int E, int NB, int chunk) {
  __shared__ int cur[1024];
  const int t = threadIdx.x;
  const int pb = blockIdx.x;
  for (int i = t; i < 1024; i += 256)
    cur[i] = (i < NB) ? (brow[i] + blockhist[pb * 1024 + i]) : 0;
  __syncthreads();
  const int e0 = pb * chunk;
  int e1 = e0 + chunk; if (e1 > E) e1 = E;
  for (int e = e0 + t; e < e1; e += 256) {
    int d = dst[e];
    int p = atomicAdd(&cur[d >> BSHIFT], 1);
    stage[p] = (unsigned)src[e] | ((unsigned)(d & 63) << 16);
  }
}

// one block per bucket: node-local deg count + scan in LDS -> rowptr, col(u16)
__global__ __launch_bounds__(256) void scatter2b_kernel(const unsigned* __restrict__ stage,
                                                        const int* __restrict__ brow,
                                                        int* __restrict__ rowptr,
                                                        unsigned short* __restrict__ col,
                                                        int N, int E) {
  __shared__ int dcnt[64];
  __shared__ int dbase[64];
  const int b = blockIdx.x;
  const int t = threadIdx.x;
  const int n0 = b << BSHIFT;
  const int lo = brow[b], hi = brow[b + 1];
  if (t < 64) dcnt[t] = 0;
  __syncthreads();
  for (int e = lo + t; e < hi; e += 256) atomicAdd(&dcnt[stage[e] >> 16], 1);
  __syncthreads();
  if (t < 64) {
    int v = dcnt[t];
    int inc = v;
    #pragma unroll
    for (int off = 1; off < 64; off <<= 1) {
      int u = __shfl_up(inc, off, 64);
      if (t >= off) inc += u;
    }
    int excl = lo + inc - v;
    dbase[t] = excl;
    dcnt[t] = 0;  // reuse as cursor
    if (n0 + t < N) rowptr[n0 + t] = excl;
  }
  if (b == 0 && t == 0) rowptr[N] = E;
  __syncthreads();
  for (int e = lo + t; e < hi; e += 256) {
    unsigned pr = stage[e];
    int d = pr >> 16;
    int p = atomicAdd(&dcnt[d], 1);
    col[dbase[d] + p] = (unsigned short)(pr & 0xffffu);
  }
}

// ------------------------- weight prep (bf16, transposed) ------------------
// grid 512: blocks 0..255 -> BT1, 256..511 -> BT2
// BT1[n][k]: k<128 -> W1_l[k][n] ; k>=128 -> W1_r[k-128][n]
// BT2[n][k]: n<128 -> W2_l[k][n] ; n>=128 -> W2_r[k][n-128]
__global__ void build_bt_kernel(const float* __restrict__ W1l, const float* __restrict__ W1r,
                                const float* __restrict__ W2l, const float* __restrict__ W2r,
                                __hip_bfloat16* __restrict__ BT1,
                                __hip_bfloat16* __restrict__ BT2) {
  int bb = blockIdx.x;
  int idx = (bb & 255) * 256 + threadIdx.x;
  int n = idx >> 8, k = idx & 255;
  if (bb < 256) {
    float v = (k < 128) ? W1l[k * 256 + n] : W1r[(k - 128) * 256 + n];
    BT1[idx] = __float2bfloat16(v);
  } else {
    float v = (n < 128) ? W2l[k * 128 + n] : W2r[k * 128 + (n - 128)];
    BT2[idx] = __float2bfloat16(v);
  }
}

// A1[i][128+j] = bf16(x[i][j]); thread handles 4 consecutive j
__global__ void convert_x_kernel(const float* __restrict__ x, __hip_bfloat16* __restrict__ A1,
                                 int total4) {
  int idx = blockIdx.x * blockDim.x + threadIdx.x;
  if (idx >= total4) return;
  int i = idx >> 5, j4 = (idx & 31) << 2;
  float4 v = *reinterpret_cast<const float4*>(x + (size_t)i * 128 + j4);
  unsigned int p0 = ((unsigned)f2bf(v.y) << 16) | f2bf(v.x);
  unsigned int p1 = ((unsigned)f2bf(v.w) << 16) | f2bf(v.z);
  uint2 pk = make_uint2(p0, p1);
  *reinterpret_cast<uint2*>(A1 + (size_t)i * 256 + 128 + j4) = pk;
}

// ------------------------------ aggregations -------------------------------
// 256-thread blocks, 4 nodes/block (one wave per node)

// A1[i][0:128] = mean over in-neighbors of A1[s][128:256]  (bf16, fp32 acc)
__global__ __launch_bounds__(256) void agg1_kernel(const int* __restrict__ rowptr,
                                                   const unsigned short* __restrict__ col,
                                                   __hip_bfloat16* __restrict__ A1, int N) {
  const int i = blockIdx.x * 4 + (threadIdx.x >> 6);
  if (i >= N) return;
  const int t = threadIdx.x & 63;
  const int beg = rowptr[i], end = rowptr[i + 1];
  float ax = 0.f, ay = 0.f;
  int e = beg;
  for (; e + 1 < end; e += 2) {
    int s0 = col[e], s1 = col[e + 1];
    unsigned int v0 = *reinterpret_cast<const unsigned int*>(A1 + (size_t)s0 * 256 + 128 + t * 2);
    unsigned int v1 = *reinterpret_cast<const unsigned int*>(A1 + (size_t)s1 * 256 + 128 + t * 2);
    ax += bfpair_lo(v0) + bfpair_lo(v1);
    ay += bfpair_hi(v0) + bfpair_hi(v1);
  }
  if (e < end) {
    int s0 = col[e];
    unsigned int v0 = *reinterpret_cast<const unsigned int*>(A1 + (size_t)s0 * 256 + 128 + t * 2);
    ax += bfpair_lo(v0);
    ay += bfpair_hi(v0);
  }
  int d = end - beg;
  float inv = 1.0f / (float)(d > 1 ? d : 1);
  unsigned int pk = ((unsigned)f2bf(ay * inv) << 16) | f2bf(ax * inv);
  *reinterpret_cast<unsigned int*>(A1 + (size_t)i * 256 + t * 2) = pk;
}

// out[i] = mean_in(hw2[:,:128]) + hw2[i,128:] + b2   (fp32 out)
__global__ __launch_bounds__(256) void agg2_kernel(const __hip_bfloat16* __restrict__ hw2,
                                                   const int* __restrict__ rowptr,
                                                   const unsigned short* __restrict__ col,
                                                   const float* __restrict__ b2,
                                                   float* __restrict__ out, int N) {
  const int i = blockIdx.x * 4 + (threadIdx.x >> 6);
  if (i >= N) return;
  const int t = threadIdx.x & 63;
  const int beg = rowptr[i], end = rowptr[i + 1];
  float ax = 0.f, ay = 0.f;
  int e = beg;
  for (; e + 1 < end; e += 2) {
    int s0 = col[e], s1 = col[e + 1];
    unsigned int v0 = *reinterpret_cast<const unsigned int*>(hw2 + (size_t)s0 * 256 + t * 2);
    unsigned int v1 = *reinterpret_cast<const unsigned int*>(hw2 + (size_t)s1 * 256 + t * 2);
    ax += bfpair_lo(v0) + bfpair_lo(v1);
    ay += bfpair_hi(v0) + bfpair_hi(v1);
  }
  if (e < end) {
    int s0 = col[e];
    unsigned int v0 = *reinterpret_cast<const unsigned int*>(hw2 + (size_t)s0 * 256 + t * 2);
    ax += bfpair_lo(v0);
    ay += bfpair_hi(v0);
  }
  int d = end - beg;
  float inv = 1.0f / (float)(d > 1 ? d : 1);
  unsigned int sv = *reinterpret_cast<const unsigned int*>(hw2 + (size_t)i * 256 + 128 + t * 2);
  float2 bb = *reinterpret_cast<const float2*>(b2 + t * 2);
  float2 r;
  r.x = ax * inv + bfpair_lo(sv) + bb.x;
  r.y = ay * inv + bfpair_hi(sv) + bb.y;
  *reinterpret_cast<float2*>(out + (size_t)i * 128 + t * 2) = r;
}

// ------------------------------ MFMA GEMM ----------------------------------
// C[M,256] = A[M,256] @ B[256,256] (+bias, relu), all bf16, fp32 accum.
// BT is B transposed: BT[n][k]. Tile 128x128, BK=32, 256 thr (4 waves, 2x2),
// per-wave 64x64 = 4x4 fragments of 16x16x32. global_load_lds width 16.
template <bool BIAS_RELU>
__global__ __launch_bounds__(256) void mfma_gemm_kernel(
    const __hip_bfloat16* __restrict__ A,   // [M][256]
    const __hip_bfloat16* __restrict__ BT,  // [256][256]
    const float* __restrict__ bias,         // [256] or null
    __hip_bfloat16* __restrict__ C,         // [M][256]
    int M) {
  __shared__ __hip_bfloat16 As[128 * 32];
  __shared__ __hip_bfloat16 Bs[128 * 32];
  const int t = threadIdx.x;
  const int lane = t & 63;
  const int w = t >> 6;
  const int bm = blockIdx.x * 128;
  const int bn = blockIdx.y * 128;
  const int wr = (w >> 1) * 64;
  const int wc = (w & 1) * 64;

  const int srow = lane >> 2;
  const int sbyte = (lane & 3) * 16;

  f32x4 acc[4][4];
  #pragma unroll
  for (int i = 0; i < 4; ++i)
    #pragma unroll
    for (int j = 0; j < 4; ++j) acc[i][j] = (f32x4)(0.f);

  const int frow_a = wr + (lane & 15);
  const int frow_b = wc + (lane & 15);
  const int fbyte = (lane >> 4) * 16;

  for (int k0 = 0; k0 < 256; k0 += 32) {
    #pragma unroll
    for (int q = 0; q < 2; ++q) {
      const int chunk = w * 2 + q;
      const int row = chunk * 16 + srow;
      int gr = bm + row;
      if (gr >= M) gr = M - 1;
      gload_lds16((const char*)A + (size_t)gr * 512 + k0 * 2 + sbyte,
                  (char*)As + chunk * 1024);
      gload_lds16((const char*)BT + (size_t)(bn + row) * 512 + k0 * 2 + sbyte,
                  (char*)Bs + chunk * 1024);
    }
    __syncthreads();
    short8 af[4], bf[4];
    #pragma unroll
    for (int i = 0; i < 4; ++i) {
      af[i] = *reinterpret_cast<const short8*>((const char*)As + (frow_a + i * 16) * 64 + fbyte);
      bf[i] = *reinterpret_cast<const short8*>((const char*)Bs + (frow_b + i * 16) * 64 + fbyte);
    }
    #pragma unroll
    for (int i = 0; i < 4; ++i)
      #pragma unroll
      for (int j = 0; j < 4; ++j)
        acc[i][j] = __builtin_amdgcn_mfma_f32_16x16x32_bf16(af[i], bf[j], acc[i][j], 0, 0, 0);
    __syncthreads();
  }

  const int crow0 = bm + wr + (lane >> 4) * 4;
  const int ccol0 = bn + wc + (lane & 15);
  float bj[4] = {0.f, 0.f, 0.f, 0.f};
  if (BIAS_RELU) {
    #pragma unroll
    for (int j = 0; j < 4; ++j) bj[j] = bias[ccol0 + j * 16];
  }
  #pragma unroll
  for (int i = 0; i < 4; ++i) {
    #pragma unroll
    for (int q = 0; q < 4; ++q) {
      const int r = crow0 + i * 16 + q;
      if (r < M) {
        #pragma unroll
        for (int j = 0; j < 4; ++j) {
          float v = acc[i][j][q];
          if (BIAS_RELU) v = fmaxf(v + bj[j], 0.f);
          C[(size_t)r * 256 + ccol0 + j * 16] = __float2bfloat16(v);
        }
      }
    }
  }
}

// ------------------------------ launcher -----------------------------------

extern "C" void kernel_launch(void* const* d_in, const int* in_sizes, int n_in,
                              void* d_out, int out_size, void* d_ws, size_t ws_size,
                              hipStream_t stream) {
  const float* x    = (const float*)d_in[0];
  const int*   edge = (const int*)d_in[1];
  const float* W1_l = (const float*)d_in[2];
  const float* b1   = (const float*)d_in[3];
  const float* W1_r = (const float*)d_in[4];
  const float* W2_l = (const float*)d_in[5];
  const float* b2   = (const float*)d_in[6];
  const float* W2_r = (const float*)d_in[7];
  float* out = (float*)d_out;

  const int N = in_sizes[0] / 128;  // 50000 (packing assumes N <= 65536)
  const int E = in_sizes[1] / 2;
  const int* srcv = edge;
  const int* dstv = edge + E;
  const int NB = (N + (1 << BSHIFT) - 1) >> BSHIFT;  // 782 (<= 1024)

  char* ws = (char*)d_ws;
  size_t off = 0;
  auto alloc = [&](size_t bytes) -> void* {
    void* p = ws + off;
    off += align_up(bytes, 256);
    return p;
  };
  int* rowptr    = (int*)alloc((size_t)(N + 1) * 4);
  int* brow      = (int*)alloc((size_t)(NB + 1) * 4);
  int* bhist     = (int*)alloc(1024 * 4);
  int* blockhist = (int*)alloc((size_t)PB * 1024 * 4);
  unsigned short* col = (unsigned short*)alloc((size_t)E * 2);
  unsigned* stage = (unsigned*)alloc((size_t)E * 4);
  __hip_bfloat16* BT1 = (__hip_bfloat16*)alloc(256 * 256 * 2);
  __hip_bfloat16* BT2 = (__hip_bfloat16*)alloc(256 * 256 * 2);
  __hip_bfloat16* A1  = (__hip_bfloat16*)alloc((size_t)N * 256 * 2);
  __hip_bfloat16* h   = (__hip_bfloat16*)alloc((size_t)N * 256 * 2);
  __hip_bfloat16* hw2 = (__hip_bfloat16*)alloc((size_t)N * 256 * 2);

  build_bt_kernel<<<512, 256, 0, stream>>>(W1_l, W1_r, W2_l, W2_r, BT1, BT2);
  convert_x_kernel<<<(N * 32 + 255) / 256, 256, 0, stream>>>(x, A1, N * 32);

  const int chunk = (E + PB - 1) / PB;
  bhist_kernel<<<PB, 256, 0, stream>>>(dstv, blockhist, E, chunk);
  colscan_kernel<<<4, 256, 0, stream>>>(blockhist, bhist);
  bscan_kernel<<<1, 256, 0, stream>>>(bhist, brow, NB);
  bin2_kernel<<<PB, 256, 0, stream>>>(srcv, dstv, brow, blockhist, stage, E, NB, chunk);
  scatter2b_kernel<<<NB, 256, 0, stream>>>(stage, brow, rowptr, col, N, E);

  agg1_kernel<<<(N + 3) / 4, 256, 0, stream>>>(rowptr, col, A1, N);

  dim3 gemm_grid((N + 127) / 128, 2);
  mfma_gemm_kernel<true><<<gemm_grid, 256, 0, stream>>>(A1, BT1, b1, h, N);
  mfma_gemm_kernel<false><<<gemm_grid, 256, 0, stream>>>(h, BT2, nullptr, hw2, N);

  agg2_kernel<<<(N + 3) / 4, 256, 0, stream>>>(hw2, rowptr, col, b2, out, N);
}

// Round 6
// 165.116 us; speedup vs baseline: 1.1906x; 1.1906x over previous
//
#include <hip/hip_runtime.h>
#include <hip/hip_bf16.h>
#include <cstdint>

// ---------------------------------------------------------------------------
// SAGE GNN, 2 layers, N=50000, E=800000, D: 128 -> 256 -> 128.
// CSR build, fully atomic-free at global scope (deterministic 2-level sort):
//   bhist:   per-block LDS hist over dst-buckets -> blockhist[pb][1024] stores
//   colscan: per-bucket serial scan over blocks -> per-(block,bucket) prefix
//   bscan:   exclusive scan of bucket totals -> brow[0..NB]
//   bin2:    cursors = brow + own prefix row (LDS), place packed 4B entries
//   scatter2b: block per bucket; per-node deg+scan in LDS -> rowptr, col(u16)
// Dense path:
//   A1[:,128:256] = bf16(x); A1[:,0:128] = mean_in(bf16 x)
//   h   = relu(A1 @ [[W1_l],[W1_r]] + b1)   bf16 MFMA GEMM, K=256,N=256
//   hw2 = h @ [W2_l | W2_r]                 bf16 MFMA GEMM
//   out = mean_in(hw2[:,:128]) + hw2[:,128:] + b2
// Aggregations: one wave per node (64-thr blocks), 4-edge unrolled gathers
// for memory-level parallelism. Packing requires N <= 65536.
// ---------------------------------------------------------------------------

static inline size_t align_up(size_t x, size_t a) { return (x + a - 1) & ~(a - 1); }

using short8 = __attribute__((ext_vector_type(8))) short;
using f32x4  = __attribute__((ext_vector_type(4))) float;

#define BSHIFT 6   // 64 nodes per bucket; NB = ceil(N/64) = 782 (<= 1024)
#define PB 98      // partition blocks for hist/bin

__device__ __forceinline__ float bfpair_lo(unsigned int v) {
  union { unsigned int i; float f; } u; u.i = v << 16; return u.f;
}
__device__ __forceinline__ float bfpair_hi(unsigned int v) {
  union { unsigned int i; float f; } u; u.i = v & 0xffff0000u; return u.f;
}
__device__ __forceinline__ unsigned short f2bf(float f) {
  union { float f; unsigned int i; } u; u.f = f;
  unsigned int r = u.i + 0x7fffu + ((u.i >> 16) & 1u);
  return (unsigned short)(r >> 16);
}

__device__ __forceinline__ void gload_lds16(const void* g, void* l) {
  __builtin_amdgcn_global_load_lds(
      (const __attribute__((address_space(1))) void*)g,
      (__attribute__((address_space(3))) void*)l, 16, 0, 0);
}

// ------------------------------- CSR build ---------------------------------

__global__ __launch_bounds__(256) void bhist_kernel(const int* __restrict__ dst,
                                                    int* __restrict__ blockhist,
                                                    int E, int chunk) {
  __shared__ int h[1024];
  const int t = threadIdx.x;
  const int pb = blockIdx.x;
  #pragma unroll
  for (int i = t; i < 1024; i += 256) h[i] = 0;
  __syncthreads();
  const int e0 = pb * chunk;
  int e1 = e0 + chunk; if (e1 > E) e1 = E;
  for (int e = e0 + t; e < e1; e += 256) atomicAdd(&h[dst[e] >> BSHIFT], 1);
  __syncthreads();
  #pragma unroll
  for (int i = t; i < 1024; i += 256) blockhist[pb * 1024 + i] = h[i];
}

// 1024 threads: for bucket i, serial scan over PB blocks (loads independent)
__global__ __launch_bounds__(256) void colscan_kernel(int* __restrict__ blockhist,
                                                      int* __restrict__ bhist) {
  const int i = blockIdx.x * 256 + threadIdx.x;  // 0..1023
  int run = 0;
  #pragma unroll 7
  for (int pb = 0; pb < PB; ++pb) {
    int v = blockhist[pb * 1024 + i];
    blockhist[pb * 1024 + i] = run;
    run += v;
  }
  bhist[i] = run;
}

// one block, 256 threads x int4: exclusive scan of bhist[0..1024) -> brow
__global__ __launch_bounds__(256) void bscan_kernel(const int* __restrict__ bhist,
                                                    int* __restrict__ brow, int NB) {
  const int t = threadIdx.x;
  int4 v = *reinterpret_cast<const int4*>(bhist + t * 4);
  int tsum = v.x + v.y + v.z + v.w;
  const int lane = t & 63, w = t >> 6;
  int inc = tsum;
  #pragma unroll
  for (int off = 1; off < 64; off <<= 1) {
    int u = __shfl_up(inc, off, 64);
    if (lane >= off) inc += u;
  }
  __shared__ int wsum[4];
  if (lane == 63) wsum[w] = inc;
  __syncthreads();
  int woff = 0;
  for (int i = 0; i < w; ++i) woff += wsum[i];
  int e0 = woff + inc - tsum;
  const int base = t * 4;
  int p[4];
  p[0] = e0;
  p[1] = e0 + v.x;
  p[2] = p[1] + v.y;
  p[3] = p[2] + v.z;
  #pragma unroll
  for (int j = 0; j < 4; ++j)
    if (base + j < NB) brow[base + j] = p[j];
  if (t == 0) brow[NB] = wsum[0] + wsum[1] + wsum[2] + wsum[3];
}

// cursors = brow + own prefix (no global atomics); place packed 4B entries
__global__ __launch_bounds__(256) void bin2_kernel(const int* __restrict__ src,
                                                   const int* __restrict__ dst,
                                                   const int* __restrict__ brow,
                                                   const int* __restrict__ blockhist,
                                                   unsigned* __restrict__ stage,
                                                   int E, int NB, int chunk) {
  __shared__ int cur[1024];
  const int t = threadIdx.x;
  const int pb = blockIdx.x;
  for (int i = t; i < 1024; i += 256)
    cur[i] = (i < NB) ? (brow[i] + blockhist[pb * 1024 + i]) : 0;
  __syncthreads();
  const int e0 = pb * chunk;
  int e1 = e0 + chunk; if (e1 > E) e1 = E;
  for (int e = e0 + t; e < e1; e += 256) {
    int d = dst[e];
    int p = atomicAdd(&cur[d >> BSHIFT], 1);
    stage[p] = (unsigned)src[e] | ((unsigned)(d & 63) << 16);
  }
}

// one block per bucket: node-local deg count + scan in LDS -> rowptr, col(u16)
__global__ __launch_bounds__(256) void scatter2b_kernel(const unsigned* __restrict__ stage,
                                                        const int* __restrict__ brow,
                                                        int* __restrict__ rowptr,
                                                        unsigned short* __restrict__ col,
                                                        int N, int E) {
  __shared__ int dcnt[64];
  __shared__ int dbase[64];
  const int b = blockIdx.x;
  const int t = threadIdx.x;
  const int n0 = b << BSHIFT;
  const int lo = brow[b], hi = brow[b + 1];
  if (t < 64) dcnt[t] = 0;
  __syncthreads();
  for (int e = lo + t; e < hi; e += 256) atomicAdd(&dcnt[stage[e] >> 16], 1);
  __syncthreads();
  if (t < 64) {
    int v = dcnt[t];
    int inc = v;
    #pragma unroll
    for (int off = 1; off < 64; off <<= 1) {
      int u = __shfl_up(inc, off, 64);
      if (t >= off) inc += u;
    }
    int excl = lo + inc - v;
    dbase[t] = excl;
    dcnt[t] = 0;  // reuse as cursor
    if (n0 + t < N) rowptr[n0 + t] = excl;
  }
  if (b == 0 && t == 0) rowptr[N] = E;
  __syncthreads();
  for (int e = lo + t; e < hi; e += 256) {
    unsigned pr = stage[e];
    int d = pr >> 16;
    int p = atomicAdd(&dcnt[d], 1);
    col[dbase[d] + p] = (unsigned short)(pr & 0xffffu);
  }
}

// ------------------------- weight prep (bf16, transposed) ------------------
__global__ void build_bt_kernel(const float* __restrict__ W1l, const float* __restrict__ W1r,
                                const float* __restrict__ W2l, const float* __restrict__ W2r,
                                __hip_bfloat16* __restrict__ BT1,
                                __hip_bfloat16* __restrict__ BT2) {
  int bb = blockIdx.x;
  int idx = (bb & 255) * 256 + threadIdx.x;
  int n = idx >> 8, k = idx & 255;
  if (bb < 256) {
    float v = (k < 128) ? W1l[k * 256 + n] : W1r[(k - 128) * 256 + n];
    BT1[idx] = __float2bfloat16(v);
  } else {
    float v = (n < 128) ? W2l[k * 128 + n] : W2r[k * 128 + (n - 128)];
    BT2[idx] = __float2bfloat16(v);
  }
}

// A1[i][128+j] = bf16(x[i][j]); thread handles 4 consecutive j
__global__ void convert_x_kernel(const float* __restrict__ x, __hip_bfloat16* __restrict__ A1,
                                 int total4) {
  int idx = blockIdx.x * blockDim.x + threadIdx.x;
  if (idx >= total4) return;
  int i = idx >> 5, j4 = (idx & 31) << 2;
  float4 v = *reinterpret_cast<const float4*>(x + (size_t)i * 128 + j4);
  unsigned int p0 = ((unsigned)f2bf(v.y) << 16) | f2bf(v.x);
  unsigned int p1 = ((unsigned)f2bf(v.w) << 16) | f2bf(v.z);
  uint2 pk = make_uint2(p0, p1);
  *reinterpret_cast<uint2*>(A1 + (size_t)i * 256 + 128 + j4) = pk;
}

// ------------------------------ aggregations -------------------------------
// one wave per node; 4-edge unrolled gathers (4 x 256B rows in flight/wave)

// A1[i][0:128] = mean over in-neighbors of A1[s][128:256]  (bf16, fp32 acc)
__global__ __launch_bounds__(64) void agg1_kernel(const int* __restrict__ rowptr,
                                                  const unsigned short* __restrict__ col,
                                                  __hip_bfloat16* __restrict__ A1) {
  const int i = blockIdx.x;
  const int t = threadIdx.x;  // 0..63
  const int beg = rowptr[i], end = rowptr[i + 1];
  float ax = 0.f, ay = 0.f;
  int e = beg;
  for (; e + 3 < end; e += 4) {
    int s0 = col[e], s1 = col[e + 1], s2 = col[e + 2], s3 = col[e + 3];
    unsigned v0 = *reinterpret_cast<const unsigned*>(A1 + (size_t)s0 * 256 + 128 + t * 2);
    unsigned v1 = *reinterpret_cast<const unsigned*>(A1 + (size_t)s1 * 256 + 128 + t * 2);
    unsigned v2 = *reinterpret_cast<const unsigned*>(A1 + (size_t)s2 * 256 + 128 + t * 2);
    unsigned v3 = *reinterpret_cast<const unsigned*>(A1 + (size_t)s3 * 256 + 128 + t * 2);
    ax += (bfpair_lo(v0) + bfpair_lo(v1)) + (bfpair_lo(v2) + bfpair_lo(v3));
    ay += (bfpair_hi(v0) + bfpair_hi(v1)) + (bfpair_hi(v2) + bfpair_hi(v3));
  }
  for (; e < end; ++e) {
    int s0 = col[e];
    unsigned v0 = *reinterpret_cast<const unsigned*>(A1 + (size_t)s0 * 256 + 128 + t * 2);
    ax += bfpair_lo(v0);
    ay += bfpair_hi(v0);
  }
  int d = end - beg;
  float inv = 1.0f / (float)(d > 1 ? d : 1);
  unsigned pk = ((unsigned)f2bf(ay * inv) << 16) | f2bf(ax * inv);
  *reinterpret_cast<unsigned*>(A1 + (size_t)i * 256 + t * 2) = pk;
}

// out[i] = mean_in(hw2[:,:128]) + hw2[i,128:] + b2   (fp32 out)
__global__ __launch_bounds__(64) void agg2_kernel(const __hip_bfloat16* __restrict__ hw2,
                                                  const int* __restrict__ rowptr,
                                                  const unsigned short* __restrict__ col,
                                                  const float* __restrict__ b2,
                                                  float* __restrict__ out) {
  const int i = blockIdx.x;
  const int t = threadIdx.x;  // 0..63
  const int beg = rowptr[i], end = rowptr[i + 1];
  float ax = 0.f, ay = 0.f;
  int e = beg;
  for (; e + 3 < end; e += 4) {
    int s0 = col[e], s1 = col[e + 1], s2 = col[e + 2], s3 = col[e + 3];
    unsigned v0 = *reinterpret_cast<const unsigned*>(hw2 + (size_t)s0 * 256 + t * 2);
    unsigned v1 = *reinterpret_cast<const unsigned*>(hw2 + (size_t)s1 * 256 + t * 2);
    unsigned v2 = *reinterpret_cast<const unsigned*>(hw2 + (size_t)s2 * 256 + t * 2);
    unsigned v3 = *reinterpret_cast<const unsigned*>(hw2 + (size_t)s3 * 256 + t * 2);
    ax += (bfpair_lo(v0) + bfpair_lo(v1)) + (bfpair_lo(v2) + bfpair_lo(v3));
    ay += (bfpair_hi(v0) + bfpair_hi(v1)) + (bfpair_hi(v2) + bfpair_hi(v3));
  }
  for (; e < end; ++e) {
    int s0 = col[e];
    unsigned v0 = *reinterpret_cast<const unsigned*>(hw2 + (size_t)s0 * 256 + t * 2);
    ax += bfpair_lo(v0);
    ay += bfpair_hi(v0);
  }
  int d = end - beg;
  float inv = 1.0f / (float)(d > 1 ? d : 1);
  unsigned sv = *reinterpret_cast<const unsigned*>(hw2 + (size_t)i * 256 + 128 + t * 2);
  float2 bb = *reinterpret_cast<const float2*>(b2 + t * 2);
  float2 r;
  r.x = ax * inv + bfpair_lo(sv) + bb.x;
  r.y = ay * inv + bfpair_hi(sv) + bb.y;
  *reinterpret_cast<float2*>(out + (size_t)i * 128 + t * 2) = r;
}

// ------------------------------ MFMA GEMM ----------------------------------
template <bool BIAS_RELU>
__global__ __launch_bounds__(256) void mfma_gemm_kernel(
    const __hip_bfloat16* __restrict__ A,   // [M][256]
    const __hip_bfloat16* __restrict__ BT,  // [256][256]
    const float* __restrict__ bias,         // [256] or null
    __hip_bfloat16* __restrict__ C,         // [M][256]
    int M) {
  __shared__ __hip_bfloat16 As[128 * 32];
  __shared__ __hip_bfloat16 Bs[128 * 32];
  const int t = threadIdx.x;
  const int lane = t & 63;
  const int w = t >> 6;
  const int bm = blockIdx.x * 128;
  const int bn = blockIdx.y * 128;
  const int wr = (w >> 1) * 64;
  const int wc = (w & 1) * 64;

  const int srow = lane >> 2;
  const int sbyte = (lane & 3) * 16;

  f32x4 acc[4][4];
  #pragma unroll
  for (int i = 0; i < 4; ++i)
    #pragma unroll
    for (int j = 0; j < 4; ++j) acc[i][j] = (f32x4)(0.f);

  const int frow_a = wr + (lane & 15);
  const int frow_b = wc + (lane & 15);
  const int fbyte = (lane >> 4) * 16;

  for (int k0 = 0; k0 < 256; k0 += 32) {
    #pragma unroll
    for (int q = 0; q < 2; ++q) {
      const int chunk = w * 2 + q;
      const int row = chunk * 16 + srow;
      int gr = bm + row;
      if (gr >= M) gr = M - 1;
      gload_lds16((const char*)A + (size_t)gr * 512 + k0 * 2 + sbyte,
                  (char*)As + chunk * 1024);
      gload_lds16((const char*)BT + (size_t)(bn + row) * 512 + k0 * 2 + sbyte,
                  (char*)Bs + chunk * 1024);
    }
    __syncthreads();
    short8 af[4], bf[4];
    #pragma unroll
    for (int i = 0; i < 4; ++i) {
      af[i] = *reinterpret_cast<const short8*>((const char*)As + (frow_a + i * 16) * 64 + fbyte);
      bf[i] = *reinterpret_cast<const short8*>((const char*)Bs + (frow_b + i * 16) * 64 + fbyte);
    }
    #pragma unroll
    for (int i = 0; i < 4; ++i)
      #pragma unroll
      for (int j = 0; j < 4; ++j)
        acc[i][j] = __builtin_amdgcn_mfma_f32_16x16x32_bf16(af[i], bf[j], acc[i][j], 0, 0, 0);
    __syncthreads();
  }

  const int crow0 = bm + wr + (lane >> 4) * 4;
  const int ccol0 = bn + wc + (lane & 15);
  float bj[4] = {0.f, 0.f, 0.f, 0.f};
  if (BIAS_RELU) {
    #pragma unroll
    for (int j = 0; j < 4; ++j) bj[j] = bias[ccol0 + j * 16];
  }
  #pragma unroll
  for (int i = 0; i < 4; ++i) {
    #pragma unroll
    for (int q = 0; q < 4; ++q) {
      const int r = crow0 + i * 16 + q;
      if (r < M) {
        #pragma unroll
        for (int j = 0; j < 4; ++j) {
          float v = acc[i][j][q];
          if (BIAS_RELU) v = fmaxf(v + bj[j], 0.f);
          C[(size_t)r * 256 + ccol0 + j * 16] = __float2bfloat16(v);
        }
      }
    }
  }
}

// ------------------------------ launcher -----------------------------------

extern "C" void kernel_launch(void* const* d_in, const int* in_sizes, int n_in,
                              void* d_out, int out_size, void* d_ws, size_t ws_size,
                              hipStream_t stream) {
  const float* x    = (const float*)d_in[0];
  const int*   edge = (const int*)d_in[1];
  const float* W1_l = (const float*)d_in[2];
  const float* b1   = (const float*)d_in[3];
  const float* W1_r = (const float*)d_in[4];
  const float* W2_l = (const float*)d_in[5];
  const float* b2   = (const float*)d_in[6];
  const float* W2_r = (const float*)d_in[7];
  float* out = (float*)d_out;

  const int N = in_sizes[0] / 128;  // 50000 (packing assumes N <= 65536)
  const int E = in_sizes[1] / 2;
  const int* srcv = edge;
  const int* dstv = edge + E;
  const int NB = (N + (1 << BSHIFT) - 1) >> BSHIFT;  // 782 (<= 1024)

  char* ws = (char*)d_ws;
  size_t off = 0;
  auto alloc = [&](size_t bytes) -> void* {
    void* p = ws + off;
    off += align_up(bytes, 256);
    return p;
  };
  int* rowptr    = (int*)alloc((size_t)(N + 1) * 4);
  int* brow      = (int*)alloc((size_t)(NB + 1) * 4);
  int* bhist     = (int*)alloc(1024 * 4);
  int* blockhist = (int*)alloc((size_t)PB * 1024 * 4);
  unsigned short* col = (unsigned short*)alloc((size_t)E * 2);
  unsigned* stage = (unsigned*)alloc((size_t)E * 4);
  __hip_bfloat16* BT1 = (__hip_bfloat16*)alloc(256 * 256 * 2);
  __hip_bfloat16* BT2 = (__hip_bfloat16*)alloc(256 * 256 * 2);
  __hip_bfloat16* A1  = (__hip_bfloat16*)alloc((size_t)N * 256 * 2);
  __hip_bfloat16* h   = (__hip_bfloat16*)alloc((size_t)N * 256 * 2);
  __hip_bfloat16* hw2 = (__hip_bfloat16*)alloc((size_t)N * 256 * 2);

  build_bt_kernel<<<512, 256, 0, stream>>>(W1_l, W1_r, W2_l, W2_r, BT1, BT2);
  convert_x_kernel<<<(N * 32 + 255) / 256, 256, 0, stream>>>(x, A1, N * 32);

  const int chunk = (E + PB - 1) / PB;
  bhist_kernel<<<PB, 256, 0, stream>>>(dstv, blockhist, E, chunk);
  colscan_kernel<<<4, 256, 0, stream>>>(blockhist, bhist);
  bscan_kernel<<<1, 256, 0, stream>>>(bhist, brow, NB);
  bin2_kernel<<<PB, 256, 0, stream>>>(srcv, dstv, brow, blockhist, stage, E, NB, chunk);
  scatter2b_kernel<<<NB, 256, 0, stream>>>(stage, brow, rowptr, col, N, E);

  agg1_kernel<<<N, 64, 0, stream>>>(rowptr, col, A1);

  dim3 gemm_grid((N + 127) / 128, 2);
  mfma_gemm_kernel<true><<<gemm_grid, 256, 0, stream>>>(A1, BT1, b1, h, N);
  mfma_gemm_kernel<false><<<gemm_grid, 256, 0, stream>>>(h, BT2, nullptr, hw2, N);

  agg2_kernel<<<N, 64, 0, stream>>>(hw2, rowptr, col, b2, out);
}

// Round 7
// 159.635 us; speedup vs baseline: 1.2315x; 1.0343x over previous
//
#include <hip/hip_runtime.h>
#include <hip/hip_bf16.h>
#include <cstdint>

// ---------------------------------------------------------------------------
// SAGE GNN, 2 layers, N=50000, E=800000, D: 128 -> 256 -> 128.
// CSR build (atomic-free at global scope):
//   bhist -> blockhist[pb][1024];  scan_all (1 block: column scan + bucket
//   exclusive scan) -> brow;  bin2 (cursors = brow + own prefix) -> stage;
//   scatter2b -> rowptr, col(u16).
// Dense path (FUSED GEMMs):
//   prep: BT1/BT2 bf16 transposed weights + A1[:,128:256] = bf16(x)
//   agg1: A1[:,0:128] = mean_in(bf16 x)
//   gemm_fused: per 64-row tile: h = relu(A1@W1+b1) -> LDS (swizzled),
//               hw2 = h@[W2_l|W2_r] -> global   (h never touches HBM)
//   agg2: out = mean_in(hw2[:,:128]) + hw2[:,128:] + b2
// ---------------------------------------------------------------------------

static inline size_t align_up(size_t x, size_t a) { return (x + a - 1) & ~(a - 1); }

using short8 = __attribute__((ext_vector_type(8))) short;
using f32x4  = __attribute__((ext_vector_type(4))) float;

#define BSHIFT 6   // 64 nodes per bucket; NB = ceil(N/64) = 782 (<= 1024)
#define PB 98      // partition blocks for hist/bin

__device__ __forceinline__ float bfpair_lo(unsigned int v) {
  union { unsigned int i; float f; } u; u.i = v << 16; return u.f;
}
__device__ __forceinline__ float bfpair_hi(unsigned int v) {
  union { unsigned int i; float f; } u; u.i = v & 0xffff0000u; return u.f;
}
__device__ __forceinline__ unsigned short f2bf(float f) {
  union { float f; unsigned int i; } u; u.f = f;
  unsigned int r = u.i + 0x7fffu + ((u.i >> 16) & 1u);
  return (unsigned short)(r >> 16);
}

__device__ __forceinline__ void gload_lds16(const void* g, void* l) {
  __builtin_amdgcn_global_load_lds(
      (const __attribute__((address_space(1))) void*)g,
      (__attribute__((address_space(3))) void*)l, 16, 0, 0);
}

// ------------------------------- CSR build ---------------------------------

__global__ __launch_bounds__(256) void bhist_kernel(const int* __restrict__ dst,
                                                    int* __restrict__ blockhist,
                                                    int E, int chunk) {
  __shared__ int h[1024];
  const int t = threadIdx.x;
  const int pb = blockIdx.x;
  #pragma unroll
  for (int i = t; i < 1024; i += 256) h[i] = 0;
  __syncthreads();
  const int e0 = pb * chunk;
  int e1 = e0 + chunk; if (e1 > E) e1 = E;
  for (int e = e0 + t; e < e1; e += 256) atomicAdd(&h[dst[e] >> BSHIFT], 1);
  __syncthreads();
  #pragma unroll
  for (int i = t; i < 1024; i += 256) blockhist[pb * 1024 + i] = h[i];
}

// ONE block, 1024 threads: per-bucket serial scan over PB blocks (in place)
// + block-wide exclusive scan of bucket totals -> brow[0..NB]
__global__ __launch_bounds__(1024) void scan_all_kernel(int* __restrict__ blockhist,
                                                        int* __restrict__ brow, int NB) {
  const int i = threadIdx.x;  // 0..1023 = bucket id
  int run = 0;
  for (int pb = 0; pb < PB; ++pb) {
    int v = blockhist[pb * 1024 + i];
    blockhist[pb * 1024 + i] = run;
    run += v;
  }
  const int lane = i & 63, w = i >> 6;  // 16 waves
  int inc = run;
  #pragma unroll
  for (int off = 1; off < 64; off <<= 1) {
    int u = __shfl_up(inc, off, 64);
    if (lane >= off) inc += u;
  }
  __shared__ int wsum[16];
  if (lane == 63) wsum[w] = inc;
  __syncthreads();
  int woff = 0;
  for (int k = 0; k < w; ++k) woff += wsum[k];
  int excl = woff + inc - run;
  if (i < NB) brow[i] = excl;
  if (i == 1023) brow[NB] = woff + inc;  // grand total (tail buckets are 0)
}

// cursors = brow + own prefix (no global atomics); place packed 4B entries
__global__ __launch_bounds__(256) void bin2_kernel(const int* __restrict__ src,
                                                   const int* __restrict__ dst,
                                                   const int* __restrict__ brow,
                                                   const int* __restrict__ blockhist,
                                                   unsigned* __restrict__ stage,
                                                   int E, int NB, int chunk) {
  __shared__ int cur[1024];
  const int t = threadIdx.x;
  const int pb = blockIdx.x;
  for (int i = t; i < 1024; i += 256)
    cur[i] = (i < NB) ? (brow[i] + blockhist[pb * 1024 + i]) : 0;
  __syncthreads();
  const int e0 = pb * chunk;
  int e1 = e0 + chunk; if (e1 > E) e1 = E;
  for (int e = e0 + t; e < e1; e += 256) {
    int d = dst[e];
    int p = atomicAdd(&cur[d >> BSHIFT], 1);
    stage[p] = (unsigned)src[e] | ((unsigned)(d & 63) << 16);
  }
}

// one block per bucket: node-local deg count + scan in LDS -> rowptr, col(u16)
__global__ __launch_bounds__(256) void scatter2b_kernel(const unsigned* __restrict__ stage,
                                                        const int* __restrict__ brow,
                                                        int* __restrict__ rowptr,
                                                        unsigned short* __restrict__ col,
                                                        int N, int E) {
  __shared__ int dcnt[64];
  __shared__ int dbase[64];
  const int b = blockIdx.x;
  const int t = threadIdx.x;
  const int n0 = b << BSHIFT;
  const int lo = brow[b], hi = brow[b + 1];
  if (t < 64) dcnt[t] = 0;
  __syncthreads();
  for (int e = lo + t; e < hi; e += 256) atomicAdd(&dcnt[stage[e] >> 16], 1);
  __syncthreads();
  if (t < 64) {
    int v = dcnt[t];
    int inc = v;
    #pragma unroll
    for (int off = 1; off < 64; off <<= 1) {
      int u = __shfl_up(inc, off, 64);
      if (t >= off) inc += u;
    }
    int excl = lo + inc - v;
    dbase[t] = excl;
    dcnt[t] = 0;  // reuse as cursor
    if (n0 + t < N) rowptr[n0 + t] = excl;
  }
  if (b == 0 && t == 0) rowptr[N] = E;
  __syncthreads();
  for (int e = lo + t; e < hi; e += 256) {
    unsigned pr = stage[e];
    int d = pr >> 16;
    int p = atomicAdd(&dcnt[d], 1);
    col[dbase[d] + p] = (unsigned short)(pr & 0xffffu);
  }
}

// --------------------- prep: weights (bf16^T) + x convert ------------------
// blocks [0,256): BT1[n][k]  k<128 -> W1_l[k][n] ; k>=128 -> W1_r[k-128][n]
// blocks [256,512): BT2[n][k]  n<128 -> W2_l[k][n] ; n>=128 -> W2_r[k][n-128]
// blocks [512,...): A1[i][128+j] = bf16(x[i][j]), 4 j per thread
__global__ __launch_bounds__(256) void prep_kernel(
    const float* __restrict__ x,
    const float* __restrict__ W1l, const float* __restrict__ W1r,
    const float* __restrict__ W2l, const float* __restrict__ W2r,
    __hip_bfloat16* __restrict__ BT1, __hip_bfloat16* __restrict__ BT2,
    __hip_bfloat16* __restrict__ A1, int total4) {
  const int bb = blockIdx.x;
  const int t = threadIdx.x;
  if (bb < 512) {
    int idx = (bb & 255) * 256 + t;
    int n = idx >> 8, k = idx & 255;
    if (bb < 256) {
      float v = (k < 128) ? W1l[k * 256 + n] : W1r[(k - 128) * 256 + n];
      BT1[idx] = __float2bfloat16(v);
    } else {
      float v = (n < 128) ? W2l[k * 128 + n] : W2r[k * 128 + (n - 128)];
      BT2[idx] = __float2bfloat16(v);
    }
    return;
  }
  int idx = (bb - 512) * 256 + t;
  if (idx >= total4) return;
  int i = idx >> 5, j4 = (idx & 31) << 2;
  float4 v = *reinterpret_cast<const float4*>(x + (size_t)i * 128 + j4);
  unsigned p0 = ((unsigned)f2bf(v.y) << 16) | f2bf(v.x);
  unsigned p1 = ((unsigned)f2bf(v.w) << 16) | f2bf(v.z);
  *reinterpret_cast<uint2*>(A1 + (size_t)i * 256 + 128 + j4) = make_uint2(p0, p1);
}

// ------------------------------ aggregations -------------------------------
// one wave per node; 4-edge unrolled gathers (4 x 256B rows in flight/wave)

__global__ __launch_bounds__(64) void agg1_kernel(const int* __restrict__ rowptr,
                                                  const unsigned short* __restrict__ col,
                                                  __hip_bfloat16* __restrict__ A1) {
  const int i = blockIdx.x;
  const int t = threadIdx.x;  // 0..63
  const int beg = rowptr[i], end = rowptr[i + 1];
  float ax = 0.f, ay = 0.f;
  int e = beg;
  for (; e + 3 < end; e += 4) {
    int s0 = col[e], s1 = col[e + 1], s2 = col[e + 2], s3 = col[e + 3];
    unsigned v0 = *reinterpret_cast<const unsigned*>(A1 + (size_t)s0 * 256 + 128 + t * 2);
    unsigned v1 = *reinterpret_cast<const unsigned*>(A1 + (size_t)s1 * 256 + 128 + t * 2);
    unsigned v2 = *reinterpret_cast<const unsigned*>(A1 + (size_t)s2 * 256 + 128 + t * 2);
    unsigned v3 = *reinterpret_cast<const unsigned*>(A1 + (size_t)s3 * 256 + 128 + t * 2);
    ax += (bfpair_lo(v0) + bfpair_lo(v1)) + (bfpair_lo(v2) + bfpair_lo(v3));
    ay += (bfpair_hi(v0) + bfpair_hi(v1)) + (bfpair_hi(v2) + bfpair_hi(v3));
  }
  for (; e < end; ++e) {
    int s0 = col[e];
    unsigned v0 = *reinterpret_cast<const unsigned*>(A1 + (size_t)s0 * 256 + 128 + t * 2);
    ax += bfpair_lo(v0);
    ay += bfpair_hi(v0);
  }
  int d = end - beg;
  float inv = 1.0f / (float)(d > 1 ? d : 1);
  unsigned pk = ((unsigned)f2bf(ay * inv) << 16) | f2bf(ax * inv);
  *reinterpret_cast<unsigned*>(A1 + (size_t)i * 256 + t * 2) = pk;
}

__global__ __launch_bounds__(64) void agg2_kernel(const __hip_bfloat16* __restrict__ hw2,
                                                  const int* __restrict__ rowptr,
                                                  const unsigned short* __restrict__ col,
                                                  const float* __restrict__ b2,
                                                  float* __restrict__ out) {
  const int i = blockIdx.x;
  const int t = threadIdx.x;  // 0..63
  const int beg = rowptr[i], end = rowptr[i + 1];
  float ax = 0.f, ay = 0.f;
  int e = beg;
  for (; e + 3 < end; e += 4) {
    int s0 = col[e], s1 = col[e + 1], s2 = col[e + 2], s3 = col[e + 3];
    unsigned v0 = *reinterpret_cast<const unsigned*>(hw2 + (size_t)s0 * 256 + t * 2);
    unsigned v1 = *reinterpret_cast<const unsigned*>(hw2 + (size_t)s1 * 256 + t * 2);
    unsigned v2 = *reinterpret_cast<const unsigned*>(hw2 + (size_t)s2 * 256 + t * 2);
    unsigned v3 = *reinterpret_cast<const unsigned*>(hw2 + (size_t)s3 * 256 + t * 2);
    ax += (bfpair_lo(v0) + bfpair_lo(v1)) + (bfpair_lo(v2) + bfpair_lo(v3));
    ay += (bfpair_hi(v0) + bfpair_hi(v1)) + (bfpair_hi(v2) + bfpair_hi(v3));
  }
  for (; e < end; ++e) {
    int s0 = col[e];
    unsigned v0 = *reinterpret_cast<const unsigned*>(hw2 + (size_t)s0 * 256 + t * 2);
    ax += bfpair_lo(v0);
    ay += bfpair_hi(v0);
  }
  int d = end - beg;
  float inv = 1.0f / (float)(d > 1 ? d : 1);
  unsigned sv = *reinterpret_cast<const unsigned*>(hw2 + (size_t)i * 256 + 128 + t * 2);
  float2 bb = *reinterpret_cast<const float2*>(b2 + t * 2);
  float2 r;
  r.x = ax * inv + bfpair_lo(sv) + bb.x;
  r.y = ay * inv + bfpair_hi(sv) + bb.y;
  *reinterpret_cast<float2*>(out + (size_t)i * 128 + t * 2) = r;
}

// --------------------------- FUSED double GEMM -----------------------------
// Per 64-row tile (256 thr, 4 waves side by side in N):
//   phase 1: h(64x256) = relu(A1_tile @ BT1^T + b1) -> hLds (bf16, swizzled)
//   phase 2: hw2(64x256) = h @ BT2^T -> global bf16
// hLds rows are 512B: XOR-swizzle 16B-slot index with (row&7) to kill the
// same-bank column pattern (16-way -> ~2-way).
__global__ __launch_bounds__(256) void gemm_fused_kernel(
    const __hip_bfloat16* __restrict__ A1,   // [M][256]
    const __hip_bfloat16* __restrict__ BT1,  // [256][256] = B1^T
    const __hip_bfloat16* __restrict__ BT2,  // [256][256] = B2^T
    const float* __restrict__ b1,            // [256]
    __hip_bfloat16* __restrict__ hw2,        // [M][256]
    int M) {
  __shared__ __hip_bfloat16 As[64 * 32];        // 4 KB
  __shared__ __hip_bfloat16 Bs[256 * 32];       // 16 KB
  __shared__ __hip_bfloat16 hLds[64 * 256];     // 32 KB, swizzled
  const int t = threadIdx.x;
  const int lane = t & 63;
  const int w = t >> 6;        // 0..3
  const int wc = w * 64;       // wave col offset
  const int bm = blockIdx.x * 64;

  const int srow4 = lane >> 2;         // 0..15
  const int sbyte = (lane & 3) * 16;   // 16B slot within 64B row
  const int fr = lane & 15;            // fragment row/col within 16
  const int fbyte = (lane >> 4) * 16;  // k-slot byte within 64B row
  const int kslot = lane >> 4;         // k-slot index (16B units)

  f32x4 acc[4][4];
  #pragma unroll
  for (int i = 0; i < 4; ++i)
    #pragma unroll
    for (int j = 0; j < 4; ++j) acc[i][j] = (f32x4)(0.f);

  // ---------------- phase 1: h = relu(A1 @ BT1^T + b1) ----------------
  for (int k0 = 0; k0 < 256; k0 += 32) {
    {  // stage A tile: 64 rows x 64B; wave w -> rows [w*16, w*16+16)
      int gr = bm + w * 16 + srow4;
      if (gr >= M) gr = M - 1;
      gload_lds16((const char*)A1 + (size_t)gr * 512 + k0 * 2 + sbyte,
                  (char*)As + w * 1024);
    }
    #pragma unroll
    for (int q = 0; q < 4; ++q) {  // stage B: 256 rows x 64B
      const int c = w * 4 + q;
      const int row = c * 16 + srow4;
      gload_lds16((const char*)BT1 + (size_t)row * 512 + k0 * 2 + sbyte,
                  (char*)Bs + c * 1024);
    }
    __syncthreads();
    short8 af[4], bf[4];
    #pragma unroll
    for (int i = 0; i < 4; ++i) {
      af[i] = *reinterpret_cast<const short8*>((const char*)As + (fr + i * 16) * 64 + fbyte);
      bf[i] = *reinterpret_cast<const short8*>((const char*)Bs + (wc + fr + i * 16) * 64 + fbyte);
    }
    #pragma unroll
    for (int i = 0; i < 4; ++i)
      #pragma unroll
      for (int j = 0; j < 4; ++j)
        acc[i][j] = __builtin_amdgcn_mfma_f32_16x16x32_bf16(af[i], bf[j], acc[i][j], 0, 0, 0);
    __syncthreads();
  }

  // epilogue 1: bias + relu -> hLds (swizzled)
  {
    const int c0 = wc + fr;
    const int r0 = (lane >> 4) * 4;
    float bj[4];
    #pragma unroll
    for (int j = 0; j < 4; ++j) bj[j] = b1[c0 + j * 16];
    #pragma unroll
    for (int i = 0; i < 4; ++i) {
      #pragma unroll
      for (int j = 0; j < 4; ++j) {
        const int c = c0 + j * 16;
        #pragma unroll
        for (int q = 0; q < 4; ++q) {
          const int r = r0 + i * 16 + q;
          float v = fmaxf(acc[i][j][q] + bj[j], 0.f);
          const int byte = r * 512 + (((c >> 3) ^ (r & 7)) << 4) + ((c & 7) << 1);
          *reinterpret_cast<__hip_bfloat16*>((char*)hLds + byte) = __float2bfloat16(v);
        }
      }
    }
  }

  // ---------------- phase 2: hw2 = h @ BT2^T ----------------
  #pragma unroll
  for (int i = 0; i < 4; ++i)
    #pragma unroll
    for (int j = 0; j < 4; ++j) acc[i][j] = (f32x4)(0.f);

  for (int k0 = 0; k0 < 256; k0 += 32) {
    #pragma unroll
    for (int q = 0; q < 4; ++q) {  // stage B2: 256 rows x 64B
      const int c = w * 4 + q;
      const int row = c * 16 + srow4;
      gload_lds16((const char*)BT2 + (size_t)row * 512 + k0 * 2 + sbyte,
                  (char*)Bs + c * 1024);
    }
    __syncthreads();  // also covers epilogue-1 ds_writes on first iter
    short8 af[4], bf[4];
    const int ks = (k0 >> 3) + kslot;  // 16B k-slot index in hLds row
    #pragma unroll
    for (int i = 0; i < 4; ++i) {
      const int ra = fr + i * 16;
      af[i] = *reinterpret_cast<const short8*>(
          (const char*)hLds + ra * 512 + ((ks ^ (ra & 7)) << 4));
      bf[i] = *reinterpret_cast<const short8*>((const char*)Bs + (wc + fr + i * 16) * 64 + fbyte);
    }
    #pragma unroll
    for (int i = 0; i < 4; ++i)
      #pragma unroll
      for (int j = 0; j < 4; ++j)
        acc[i][j] = __builtin_amdgcn_mfma_f32_16x16x32_bf16(af[i], bf[j], acc[i][j], 0, 0, 0);
    __syncthreads();
  }

  // epilogue 2: write hw2 tile
  {
    const int c0 = wc + fr;
    const int r0 = (lane >> 4) * 4;
    #pragma unroll
    for (int i = 0; i < 4; ++i) {
      #pragma unroll
      for (int q = 0; q < 4; ++q) {
        const int r = bm + r0 + i * 16 + q;
        if (r < M) {
          #pragma unroll
          for (int j = 0; j < 4; ++j)
            hw2[(size_t)r * 256 + c0 + j * 16] = __float2bfloat16(acc[i][j][q]);
        }
      }
    }
  }
}

// ------------------------------ launcher -----------------------------------

extern "C" void kernel_launch(void* const* d_in, const int* in_sizes, int n_in,
                              void* d_out, int out_size, void* d_ws, size_t ws_size,
                              hipStream_t stream) {
  const float* x    = (const float*)d_in[0];
  const int*   edge = (const int*)d_in[1];
  const float* W1_l = (const float*)d_in[2];
  const float* b1   = (const float*)d_in[3];
  const float* W1_r = (const float*)d_in[4];
  const float* W2_l = (const float*)d_in[5];
  const float* b2   = (const float*)d_in[6];
  const float* W2_r = (const float*)d_in[7];
  float* out = (float*)d_out;

  const int N = in_sizes[0] / 128;  // 50000 (packing assumes N <= 65536)
  const int E = in_sizes[1] / 2;
  const int* srcv = edge;
  const int* dstv = edge + E;
  const int NB = (N + (1 << BSHIFT) - 1) >> BSHIFT;  // 782 (<= 1024)

  char* ws = (char*)d_ws;
  size_t off = 0;
  auto alloc = [&](size_t bytes) -> void* {
    void* p = ws + off;
    off += align_up(bytes, 256);
    return p;
  };
  int* rowptr    = (int*)alloc((size_t)(N + 1) * 4);
  int* brow      = (int*)alloc((size_t)(NB + 1) * 4);
  int* blockhist = (int*)alloc((size_t)PB * 1024 * 4);
  unsigned short* col = (unsigned short*)alloc((size_t)E * 2);
  unsigned* stage = (unsigned*)alloc((size_t)E * 4);
  __hip_bfloat16* BT1 = (__hip_bfloat16*)alloc(256 * 256 * 2);
  __hip_bfloat16* BT2 = (__hip_bfloat16*)alloc(256 * 256 * 2);
  __hip_bfloat16* A1  = (__hip_bfloat16*)alloc((size_t)N * 256 * 2);
  __hip_bfloat16* hw2 = (__hip_bfloat16*)alloc((size_t)N * 256 * 2);

  const int conv_blocks = (N * 32 + 255) / 256;
  prep_kernel<<<512 + conv_blocks, 256, 0, stream>>>(x, W1_l, W1_r, W2_l, W2_r,
                                                     BT1, BT2, A1, N * 32);

  const int chunk = (E + PB - 1) / PB;
  bhist_kernel<<<PB, 256, 0, stream>>>(dstv, blockhist, E, chunk);
  scan_all_kernel<<<1, 1024, 0, stream>>>(blockhist, brow, NB);
  bin2_kernel<<<PB, 256, 0, stream>>>(srcv, dstv, brow, blockhist, stage, E, NB, chunk);
  scatter2b_kernel<<<NB, 256, 0, stream>>>(stage, brow, rowptr, col, N, E);

  agg1_kernel<<<N, 64, 0, stream>>>(rowptr, col, A1);

  gemm_fused_kernel<<<(N + 63) / 64, 256, 0, stream>>>(A1, BT1, BT2, b1, hw2, N);

  agg2_kernel<<<N, 64, 0, stream>>>(hw2, rowptr, col, b2, out);
}